// Round 9
// baseline (69.516 us; speedup 1.0000x reference)
//
#include <hip/hip_runtime.h>
#include <math.h>

// Problem constants (fixed by the harness's setup_inputs)
#define HDIM 256
#define NDIM 64
#define LDIM 8192
#define LF   4097          // L/2 + 1
#define MDIM 4096          // L/2  (complex FFT size)
#define LOG2M 12
#define ILP  2             // l-values per thread in cauchy (8 blocks/CU)

typedef float v2f __attribute__((ext_vector_type(2)));

__device__ __forceinline__ float rlane(float v, int n) {
    return __int_as_float(__builtin_amdgcn_readlane(__float_as_int(v), n));
}

// ---------------------------------------------------------------------------
// Stage A: Cauchy + Woodbury -> k_f[h][l].
// R9 = R8 (VGPR-resident constants broadcast via v_readlane: zero memory
// traffic in the n-loop) + R6's occupancy (ILP=2 -> 2048 blocks -> 8
// waves/SIMD, launch_bounds(256,8) caps VGPR at 64).
// v_pk_fma_f32 is HALF-RATE on CDNA4 (fp32 peak 157 TF = scalar rate) —
// packing is code density only; idle-issue reduction must come from TLP.
//   U_ab = sum_n v_ab / D_n,  D = 2(1-omega) - w*dt*(1+omega)
//   k_f  = 2 dt U00 - (dt(1+w)U01)(2 dt U10) / (1 + dt(1+w)U11)
// ---------------------------------------------------------------------------
__global__ __launch_bounds__(256, 8) void cauchy_kernel(
    const float* __restrict__ log_dt,
    const float* __restrict__ C_re, const float* __restrict__ C_im,
    const float* __restrict__ B_re, const float* __restrict__ B_im,
    const float* __restrict__ P_re, const float* __restrict__ P_im,
    const float* __restrict__ Q_re, const float* __restrict__ Q_im,
    const float* __restrict__ w_re, const float* __restrict__ w_im,
    float2* __restrict__ kf)
{
    const int h    = blockIdx.y;
    const int tid  = threadIdx.x;
    const int lane = tid & 63;
    const float dt = expf(log_dt[h]);

    // ---- per-wave constant prologue: lane i holds pole i's constants ----
    const int idx = h * NDIM + lane;
    const float Br = B_re[idx], Bi = B_im[idx];
    const float Cr = C_re[idx], Ci = C_im[idx];
    const float Pr = P_re[idx], Pi = P_im[idx];
    const float Qr = Q_re[idx], Qi = Q_im[idx];
    const float wdr = w_re[idx] * dt, wdi = w_im[idx] * dt;
    const float v00r = Cr*Br - Ci*Bi, v00i = Cr*Bi + Ci*Br;   // C*B
    const float v01r = Cr*Pr - Ci*Pi, v01i = Cr*Pi + Ci*Pr;   // C*P
    const float v10r = Qr*Br - Qi*Bi, v10i = Qr*Bi + Qi*Br;   // Q*B
    const float v11r = Qr*Pr - Qi*Pi, v11i = Qr*Pi + Qi*Pr;   // Q*P

    // Nyquist bin (l = 4096): omega=-1 -> D=4, (1+omega)=0 =>
    // k_f = 0.5*dt*sum_n v00[n]; Woodbury term vanishes.
    if (blockIdx.x == 0 && tid < 64) {
        float sr = v00r, si = v00i;
        #pragma unroll
        for (int off = 32; off > 0; off >>= 1) {
            sr += __shfl_xor(sr, off);
            si += __shfl_xor(si, off);
        }
        if (tid == 0)
            kf[h * LF + MDIM] = make_float2(0.5f * dt * sr, 0.5f * dt * si);
    }

    // per-thread l-values: l = blockIdx.x*512 + k*256 + tid, k = 0..1 (<4096)
    const int lbase = blockIdx.x * (ILP * 256) + tid;

    v2f opw[ILP], td[ILP];
    #pragma unroll
    for (int k = 0; k < ILP; ++k) {
        const int l = lbase + k * 256;
        const float theta = (6.28318530717958647692f / (float)LDIM) * (float)l;
        float sn, cs;
        sincosf(theta, &sn, &cs);
        opw[k] = (v2f){1.f + cs, -sn};                 // 1 + omega
        td[k]  = (v2f){2.f * (1.f - cs), 2.f * sn};    // 2*(1 - omega)
    }

    v2f u00[ILP] = {}, u01[ILP] = {}, u10[ILP] = {}, u11[ILP] = {};

    #pragma unroll 4
    for (int n = 0; n < NDIM; ++n) {
        // broadcast pole n's constants: 10 v_readlane, no memory, no latency
        const v2f wp  = (v2f){rlane(wdr,  n), rlane(wdi,  n)};
        const v2f p00 = (v2f){rlane(v00r, n), rlane(v00i, n)};
        const v2f p01 = (v2f){rlane(v01r, n), rlane(v01i, n)};
        const v2f p10 = (v2f){rlane(v10r, n), rlane(v10i, n)};
        const v2f p11 = (v2f){rlane(v11r, n), rlane(v11i, n)};

        #pragma unroll
        for (int k = 0; k < ILP; ++k) {
            // D = td - wr*(or,oi) + wi*(oi,-or)  [D = td - w*(1+omega)]
            v2f D = td[k];
            asm("v_pk_fma_f32 %0, %1, %2, %0 op_sel:[0,0,0] op_sel_hi:[0,1,1] neg_lo:[1,0,0] neg_hi:[1,0,0]"
                : "+v"(D) : "s"(wp), "v"(opw[k]));
            asm("v_pk_fma_f32 %0, %1, %2, %0 op_sel:[1,1,0] op_sel_hi:[1,0,1] neg_hi:[0,1,0]"
                : "+v"(D) : "s"(wp), "v"(opw[k]));

            const float den = fmaf(D.x, D.x, D.y * D.y);
            const float r   = __builtin_amdgcn_rcpf(den);
            const v2f  rr   = (v2f){r, r};
            v2f m;                               // m = D*r ; 1/D = (m.x,-m.y)
            asm("v_pk_mul_f32 %0, %1, %2" : "=v"(m) : "v"(D), "v"(rr));

            // u += p * (m.x, -m.y)  (complex, two pk_fma per accumulator)
            asm("v_pk_fma_f32 %0, %1, %2, %0 op_sel:[0,0,0] op_sel_hi:[0,1,1] neg_hi:[0,1,0]"
                : "+v"(u00[k]) : "s"(p00), "v"(m));
            asm("v_pk_fma_f32 %0, %1, %2, %0 op_sel:[1,1,0] op_sel_hi:[1,0,1]"
                : "+v"(u00[k]) : "s"(p00), "v"(m));
            asm("v_pk_fma_f32 %0, %1, %2, %0 op_sel:[0,0,0] op_sel_hi:[0,1,1] neg_hi:[0,1,0]"
                : "+v"(u01[k]) : "s"(p01), "v"(m));
            asm("v_pk_fma_f32 %0, %1, %2, %0 op_sel:[1,1,0] op_sel_hi:[1,0,1]"
                : "+v"(u01[k]) : "s"(p01), "v"(m));
            asm("v_pk_fma_f32 %0, %1, %2, %0 op_sel:[0,0,0] op_sel_hi:[0,1,1] neg_hi:[0,1,0]"
                : "+v"(u10[k]) : "s"(p10), "v"(m));
            asm("v_pk_fma_f32 %0, %1, %2, %0 op_sel:[1,1,0] op_sel_hi:[1,0,1]"
                : "+v"(u10[k]) : "s"(p10), "v"(m));
            asm("v_pk_fma_f32 %0, %1, %2, %0 op_sel:[0,0,0] op_sel_hi:[0,1,1] neg_hi:[0,1,0]"
                : "+v"(u11[k]) : "s"(p11), "v"(m));
            asm("v_pk_fma_f32 %0, %1, %2, %0 op_sel:[1,1,0] op_sel_hi:[1,0,1]"
                : "+v"(u11[k]) : "s"(p11), "v"(m));
        }
    }

    #pragma unroll
    for (int k = 0; k < ILP; ++k) {
        const int l = lbase + k * 256;
        const float two_dt = 2.f * dt;
        const float r00r = two_dt * u00[k].x, r00i = two_dt * u00[k].y;
        const float r10r = two_dt * u10[k].x, r10i = two_dt * u10[k].y;
        // r01 = dt*(1+omega)*U01 ; 1 + r11 = 1 + dt*(1+omega)*U11
        const float r01r = dt * (opw[k].x * u01[k].x - opw[k].y * u01[k].y);
        const float r01i = dt * (opw[k].x * u01[k].y + opw[k].y * u01[k].x);
        const float d_r  = 1.f + dt * (opw[k].x * u11[k].x - opw[k].y * u11[k].y);
        const float d_i  =       dt * (opw[k].x * u11[k].y + opw[k].y * u11[k].x);

        const float numr = r01r * r10r - r01i * r10i;
        const float numi = r01r * r10i + r01i * r10r;
        const float dd   = fmaf(d_r, d_r, d_i * d_i);
        const float rr2  = __builtin_amdgcn_rcpf(dd);
        const float cr = (numr * d_r + numi * d_i) * rr2;
        const float ci = (numi * d_r - numr * d_i) * rr2;

        kf[h * LF + l] = make_float2(r00r - cr, r00i - ci);
    }
}

// ---------------------------------------------------------------------------
// Stage B: inverse rfft via complex iFFT of size M = L/2. (unchanged, ~5 us)
// ---------------------------------------------------------------------------
__global__ __launch_bounds__(1024) void ifft_kernel(
    const float2* __restrict__ kf, float2* __restrict__ out2)
{
    __shared__ float2 S[MDIM];          // 32 KB

    const int h   = blockIdx.x;
    const int tid = threadIdx.x;
    const float2* K = kf + (size_t)h * LF;

    // ---- build Z (bit-reversed) from Hermitian half-spectrum ----
    for (int l = tid; l <= MDIM / 2; l += 1024) {
        const float2 Kl = K[l];
        const float2 Km = K[MDIM - l];
        const float Ar = 0.5f * (Kl.x + Km.x);
        const float Ai = 0.5f * (Kl.y - Km.y);
        const float Br = 0.5f * (Kl.x - Km.x);
        const float Bi = 0.5f * (Kl.y + Km.y);
        const float phi = (6.28318530717958647692f / (float)LDIM) * (float)l;
        float s, c;
        sincosf(phi, &s, &c);
        const float Or = c * Br - s * Bi;
        const float Oi = c * Bi + s * Br;
        const int bl = (int)(__brev((unsigned)l) >> (32 - LOG2M));
        S[bl] = make_float2(Ar - Oi, Ai + Or);
        if (l > 0 && l < MDIM / 2) {
            const int bm = (int)(__brev((unsigned)(MDIM - l)) >> (32 - LOG2M));
            S[bm] = make_float2(Ar + Oi, Or - Ai);
        }
    }

    // ---- 12 radix-2 DIT stages, inverse twiddles ----
    #pragma unroll
    for (int stage = 0; stage < LOG2M; ++stage) {
        const int half = 1 << stage;
        __syncthreads();
        #pragma unroll 2
        for (int t = tid; t < MDIM / 2; t += 1024) {
            const int pos = t & (half - 1);
            const int i0  = ((t & ~(half - 1)) << 1) | pos;
            const int i1  = i0 + half;
            const float ang = (3.14159265358979323846f / (float)half) * (float)pos;
            float s, c;
            sincosf(ang, &s, &c);
            const float2 a = S[i0];
            const float2 b = S[i1];
            const float tr = c * b.x - s * b.y;
            const float ti = c * b.y + s * b.x;
            S[i0] = make_float2(a.x + tr, a.y + ti);
            S[i1] = make_float2(a.x - tr, a.y - ti);
        }
    }
    __syncthreads();

    const float invM = 1.f / (float)MDIM;
    for (int n = tid; n < MDIM; n += 1024) {
        const float2 z = S[n];
        out2[(size_t)h * MDIM + n] = make_float2(z.x * invM, z.y * invM);
    }
}

extern "C" void kernel_launch(void* const* d_in, const int* in_sizes, int n_in,
                              void* d_out, int out_size, void* d_ws, size_t ws_size,
                              hipStream_t stream)
{
    const float* log_dt = (const float*)d_in[0];
    const float* C_re   = (const float*)d_in[1];
    const float* C_im   = (const float*)d_in[2];
    const float* B_re   = (const float*)d_in[3];
    const float* B_im   = (const float*)d_in[4];
    const float* P_re   = (const float*)d_in[5];
    const float* P_im   = (const float*)d_in[6];
    const float* Q_re   = (const float*)d_in[7];
    const float* Q_im   = (const float*)d_in[8];
    const float* w_re   = (const float*)d_in[9];
    const float* w_im   = (const float*)d_in[10];

    float2* kf = (float2*)d_ws;          // HDIM * LF * 8 B = 8.39 MB (in ws)
    float2* out2 = (float2*)d_out;

    dim3 grid1(MDIM / (ILP * 256), HDIM);   // 8 x 256 = 2048 blocks, zero waste
    cauchy_kernel<<<grid1, 256, 0, stream>>>(log_dt, C_re, C_im, B_re, B_im,
                                             P_re, P_im, Q_re, Q_im,
                                             w_re, w_im, kf);

    ifft_kernel<<<HDIM, 1024, 0, stream>>>(kf, out2);
}

// Round 11
// 60.866 us; speedup vs baseline: 1.1421x; 1.1421x over previous
//
#include <hip/hip_runtime.h>
#include <hip/hip_fp16.h>
#include <math.h>

// Problem constants (fixed by the harness's setup_inputs)
#define HDIM 256
#define NDIM 64
#define LDIM 8192
#define LF   4097          // L/2 + 1
#define MDIM 4096          // L/2  (complex FFT size)
#define LOG2M 12

typedef _Float16 f16x8 __attribute__((ext_vector_type(8)));
typedef float    f32x4 __attribute__((ext_vector_type(4)));

// round-nearest f32 pair -> packed f16 dword (2x v_cvt_f16_f32 + pack)
__device__ __forceinline__ int cvt_pk_f16(float lo, float hi) {
    union { __half2 h; int i; } u;
    u.h = __floats2half2_rn(lo, hi);
    return u.i;
}

// ---------------------------------------------------------------------------
// Stage A (R11): MFMA Cauchy, fp16 operands (R10 was bf16: absmax 1.0e-1 =
// 2.3x over threshold, pure quantization. fp16 = +3 mantissa bits = 8x lower
// rounding at the same instruction count/layout; 1/D in [~0.1,~1e3] and v in
// [~1e-2,~10] fit fp16 range easily).
//   Contraction U_ab[l] = sum_n v_ab[n] * (1/D[l,n]) as a K=128 matmul:
//     B[k][col] (k=2n+p): p=0 -> Re(1/D[l,n]), p=1 -> Im(1/D[l,n]); col = l.
//     A[m][k]   (m=2a+c): c=0 row: (vr, -vi); c=1 row: (vi, vr); rows 8..15=0.
//   4 chained mfma_f32_16x16x32_f16 over K. Per-lane (row/col = lane&15,
//   k = 8*(lane>>4)+j): B-build needs only per-lane-resident wdt constants
//   (no broadcasts/LDS/s_load in the hot loop); C: col=lane&15=l, lanes 0-15
//   hold U00,U01, lanes 16-31 hold U10,U11 -> one shfl_xor(16) + Woodbury.
// ---------------------------------------------------------------------------
__global__ __launch_bounds__(256, 6) void cauchy_kernel(
    const float* __restrict__ log_dt,
    const float* __restrict__ C_re, const float* __restrict__ C_im,
    const float* __restrict__ B_re, const float* __restrict__ B_im,
    const float* __restrict__ P_re, const float* __restrict__ P_im,
    const float* __restrict__ Q_re, const float* __restrict__ Q_im,
    const float* __restrict__ w_re, const float* __restrict__ w_im,
    float2* __restrict__ kf)
{
    const int h    = blockIdx.y;
    const int tid  = threadIdx.x;
    const int lane = tid & 63;
    const int wave = tid >> 6;
    const int g    = lane >> 4;     // k-block index (0..3)
    const int m    = lane & 15;     // col (l-offset) and A-row index
    const float dt = expf(log_dt[h]);
    const int hb   = h * NDIM;

    // Nyquist bin (l = 4096): omega=-1 -> D=4, (1+omega)=0 =>
    // k_f = 0.5*dt*sum_n v00[n]; Woodbury term vanishes.
    if (blockIdx.x == 0 && tid < 64) {
        const float br = B_re[hb + lane], bi = B_im[hb + lane];
        const float cr = C_re[hb + lane], ci = C_im[hb + lane];
        float sr = cr * br - ci * bi;
        float si = cr * bi + ci * br;
        #pragma unroll
        for (int off = 32; off > 0; off >>= 1) {
            sr += __shfl_xor(sr, off);
            si += __shfl_xor(si, off);
        }
        if (tid == 0)
            kf[h * LF + MDIM] = make_float2(0.5f * dt * sr, 0.5f * dt * si);
    }

    // ---- per-lane constants: wdt for this lane's 16 poles + A fragments ----
    float wr_[16], wi_[16];
    int   av[4][4];                 // A fragment dwords (2 f16 each)
    {
        const bool arow = (m < 8);
        const int  ai   = m >> 1;   // 0:C*B 1:C*P 2:Q*B 3:Q*P
        const int  c    = m & 1;    // 0:re-row 1:im-row
        const float* fre = (ai >= 2) ? Q_re : C_re;
        const float* fim = (ai >= 2) ? Q_im : C_im;
        const float* sre = (ai & 1) ? P_re : B_re;
        const float* sim = (ai & 1) ? P_im : B_im;
        #pragma unroll
        for (int q = 0; q < 4; ++q) {
            #pragma unroll
            for (int t = 0; t < 4; ++t) {
                const int n = hb + 16 * q + 4 * g + t;
                wr_[q * 4 + t] = w_re[n] * dt;
                wi_[q * 4 + t] = w_im[n] * dt;
                float e0 = 0.f, e1 = 0.f;
                if (arow) {
                    const float fr = fre[n], fi = fim[n];
                    const float s2r = sre[n], s2i = sim[n];
                    const float vr = fr * s2r - fi * s2i;
                    const float vi = fr * s2i + fi * s2r;
                    e0 = c ? vi : vr;
                    e1 = c ? vr : -vi;
                }
                av[q][t] = cvt_pk_f16(e0, e1);
            }
        }
    }

    // wave handles 8 l-tiles of 16: l = bx*512 + wave*128 + t8*16 + m
    const int lbase = blockIdx.x * 512 + wave * 128 + m;

    for (int t8 = 0; t8 < 8; ++t8) {
        const int l = lbase + t8 * 16;
        const float theta = (6.28318530717958647692f / (float)LDIM) * (float)l;
        float sn, cs;
        sincosf(theta, &sn, &cs);
        const float ox = 1.f + cs, oy = -sn;          // 1 + omega
        const float tx = 2.f * (1.f - cs), ty = 2.f * sn;  // 2*(1 - omega)

        f32x4 acc = {0.f, 0.f, 0.f, 0.f};
        #pragma unroll
        for (int q = 0; q < 4; ++q) {
            int bv[4];
            #pragma unroll
            for (int t = 0; t < 4; ++t) {
                const float wr = wr_[q * 4 + t], wi = wi_[q * 4 + t];
                // D = 2(1-omega) - wdt*(1+omega)
                const float Dr = tx - (wr * ox - wi * oy);
                const float Di = ty - (wr * oy + wi * ox);
                const float den = fmaf(Dr, Dr, Di * Di);
                const float rc = __builtin_amdgcn_rcpf(den);
                bv[t] = cvt_pk_f16(Dr * rc, -(Di * rc));   // (Re,Im) of 1/D
            }
            union { int i[4]; f16x8 v; } ua, ub;
            ua.i[0] = av[q][0]; ua.i[1] = av[q][1];
            ua.i[2] = av[q][2]; ua.i[3] = av[q][3];
            ub.i[0] = bv[0]; ub.i[1] = bv[1]; ub.i[2] = bv[2]; ub.i[3] = bv[3];
            acc = __builtin_amdgcn_mfma_f32_16x16x32_f16(ua.v, ub.v, acc, 0, 0, 0);
        }

        // ---- epilogue: gather 8 U-components per l, Woodbury, store ----
        const float o0 = __shfl_xor(acc[0], 16);
        const float o1 = __shfl_xor(acc[1], 16);
        const float o2 = __shfl_xor(acc[2], 16);
        const float o3 = __shfl_xor(acc[3], 16);
        if (lane < 16) {
            // rows 0-3 (this lane): U00.re, U00.im, U01.re, U01.im
            // rows 4-7 (lane+16)  : U10.re, U10.im, U11.re, U11.im
            const float two_dt = 2.f * dt;
            const float r00r = two_dt * acc[0], r00i = two_dt * acc[1];
            const float r10r = two_dt * o0,     r10i = two_dt * o1;
            const float r01r = dt * (ox * acc[2] - oy * acc[3]);
            const float r01i = dt * (ox * acc[3] + oy * acc[2]);
            const float d_r  = 1.f + dt * (ox * o2 - oy * o3);
            const float d_i  =       dt * (ox * o3 + oy * o2);

            const float numr = r01r * r10r - r01i * r10i;
            const float numi = r01r * r10i + r01i * r10r;
            const float dd   = fmaf(d_r, d_r, d_i * d_i);
            const float rr2  = __builtin_amdgcn_rcpf(dd);
            const float cr = (numr * d_r + numi * d_i) * rr2;
            const float ci = (numi * d_r - numr * d_i) * rr2;

            kf[h * LF + l] = make_float2(r00r - cr, r00i - ci);
        }
    }
}

// ---------------------------------------------------------------------------
// Stage B: inverse rfft via complex iFFT of size M = L/2. (unchanged, ~5 us)
// ---------------------------------------------------------------------------
__global__ __launch_bounds__(1024) void ifft_kernel(
    const float2* __restrict__ kf, float2* __restrict__ out2)
{
    __shared__ float2 S[MDIM];          // 32 KB

    const int h   = blockIdx.x;
    const int tid = threadIdx.x;
    const float2* K = kf + (size_t)h * LF;

    // ---- build Z (bit-reversed) from Hermitian half-spectrum ----
    for (int l = tid; l <= MDIM / 2; l += 1024) {
        const float2 Kl = K[l];
        const float2 Km = K[MDIM - l];
        const float Ar = 0.5f * (Kl.x + Km.x);
        const float Ai = 0.5f * (Kl.y - Km.y);
        const float Br = 0.5f * (Kl.x - Km.x);
        const float Bi = 0.5f * (Kl.y + Km.y);
        const float phi = (6.28318530717958647692f / (float)LDIM) * (float)l;
        float s, c;
        sincosf(phi, &s, &c);
        const float Or = c * Br - s * Bi;
        const float Oi = c * Bi + s * Br;
        const int bl = (int)(__brev((unsigned)l) >> (32 - LOG2M));
        S[bl] = make_float2(Ar - Oi, Ai + Or);
        if (l > 0 && l < MDIM / 2) {
            const int bm = (int)(__brev((unsigned)(MDIM - l)) >> (32 - LOG2M));
            S[bm] = make_float2(Ar + Oi, Or - Ai);
        }
    }

    // ---- 12 radix-2 DIT stages, inverse twiddles ----
    #pragma unroll
    for (int stage = 0; stage < LOG2M; ++stage) {
        const int half = 1 << stage;
        __syncthreads();
        #pragma unroll 2
        for (int t = tid; t < MDIM / 2; t += 1024) {
            const int pos = t & (half - 1);
            const int i0  = ((t & ~(half - 1)) << 1) | pos;
            const int i1  = i0 + half;
            const float ang = (3.14159265358979323846f / (float)half) * (float)pos;
            float s, c;
            sincosf(ang, &s, &c);
            const float2 a = S[i0];
            const float2 b = S[i1];
            const float tr = c * b.x - s * b.y;
            const float ti = c * b.y + s * b.x;
            S[i0] = make_float2(a.x + tr, a.y + ti);
            S[i1] = make_float2(a.x - tr, a.y - ti);
        }
    }
    __syncthreads();

    const float invM = 1.f / (float)MDIM;
    for (int n = tid; n < MDIM; n += 1024) {
        const float2 z = S[n];
        out2[(size_t)h * MDIM + n] = make_float2(z.x * invM, z.y * invM);
    }
}

extern "C" void kernel_launch(void* const* d_in, const int* in_sizes, int n_in,
                              void* d_out, int out_size, void* d_ws, size_t ws_size,
                              hipStream_t stream)
{
    const float* log_dt = (const float*)d_in[0];
    const float* C_re   = (const float*)d_in[1];
    const float* C_im   = (const float*)d_in[2];
    const float* B_re   = (const float*)d_in[3];
    const float* B_im   = (const float*)d_in[4];
    const float* P_re   = (const float*)d_in[5];
    const float* P_im   = (const float*)d_in[6];
    const float* Q_re   = (const float*)d_in[7];
    const float* Q_im   = (const float*)d_in[8];
    const float* w_re   = (const float*)d_in[9];
    const float* w_im   = (const float*)d_in[10];

    float2* kf = (float2*)d_ws;          // HDIM * LF * 8 B = 8.39 MB (in ws)
    float2* out2 = (float2*)d_out;

    dim3 grid1(8, HDIM);                 // 8 x 256 = 2048 blocks, 512 l each
    cauchy_kernel<<<grid1, 256, 0, stream>>>(log_dt, C_re, C_im, B_re, B_im,
                                             P_re, P_im, Q_re, Q_im,
                                             w_re, w_im, kf);

    ifft_kernel<<<HDIM, 1024, 0, stream>>>(kf, out2);
}

// Round 12
// 50.820 us; speedup vs baseline: 1.3679x; 1.1977x over previous
//
#include <hip/hip_runtime.h>
#include <hip/hip_fp16.h>
#include <math.h>

// Problem constants (fixed by the harness's setup_inputs)
#define HDIM 256
#define NDIM 64
#define LDIM 8192
#define LF   4097          // L/2 + 1
#define MDIM 4096          // L/2  (complex FFT size)
#define LOG2M 12

typedef _Float16 f16x8 __attribute__((ext_vector_type(8)));
typedef float    f32x4 __attribute__((ext_vector_type(4)));

// round-nearest f32 pair -> packed f16 dword
__device__ __forceinline__ int cvt_pk_f16(float lo, float hi) {
    union { __half2 h; int i; } u;
    u.h = __floats2half2_rn(lo, hi);
    return u.i;
}

// ---------------------------------------------------------------------------
// Stage A (R12): MFMA Cauchy with z-substitution.
//   omega = e^{-i theta}:  (1-omega)/(1+omega) = i tan(theta/2)  =>
//   D = 2(1-omega) - wdt(1+omega) = (1+omega) * (i*zt - wdt), zt = 2tan(th/2).
//   Pull 1/(1+omega) out of the contraction:
//     G[l,n] = 1/(i*zt - wdt) = (nwr - i*(zt-wi)) / ((zt-wi)^2 + nwr^2),
//       nwr = -w_re*dt (>0), wi = w_im*dt      [sub+mul+fma+rcp+2mul per cell]
//     V_ab[l] = sum_n v_ab[n] G[l,n]           [MFMA, K=128 re/im packing]
//     k_f = E * [V00 - dt*V01*V10 / (1 + dt*V11)],  E = dt*(1, zt/2).
//   Twiddle: half-angle (ch,sh) rotated by (cos,sin)(pi/512) per 16-l tile;
//   zt = 2*sh*rcp(ch). No sincosf in the loop; no cancellation near th=pi.
//   MFMA layout identical to R11 (empirically verified): B col = lane&15 = l,
//   k = 8*(lane>>4)+j; C rows 4*(lane>>4)+reg; lanes 0-15 hold V00,V01,
//   lanes 16-31 hold V10,V11 -> one shfl_xor(16) + Woodbury in lanes 0-15.
// ---------------------------------------------------------------------------
__global__ __launch_bounds__(256, 6) void cauchy_kernel(
    const float* __restrict__ log_dt,
    const float* __restrict__ C_re, const float* __restrict__ C_im,
    const float* __restrict__ B_re, const float* __restrict__ B_im,
    const float* __restrict__ P_re, const float* __restrict__ P_im,
    const float* __restrict__ Q_re, const float* __restrict__ Q_im,
    const float* __restrict__ w_re, const float* __restrict__ w_im,
    float2* __restrict__ kf)
{
    const int h    = blockIdx.y;
    const int tid  = threadIdx.x;
    const int lane = tid & 63;
    const int wave = tid >> 6;
    const int g    = lane >> 4;     // k-block index (0..3)
    const int m    = lane & 15;     // col (l-offset) and A-row index
    const float dt = expf(log_dt[h]);
    const int hb   = h * NDIM;

    // Nyquist bin (l = 4096): omega=-1 -> D=4, (1+omega)=0 =>
    // k_f = 0.5*dt*sum_n v00[n]; Woodbury term vanishes.
    if (blockIdx.x == 0 && tid < 64) {
        const float br = B_re[hb + lane], bi = B_im[hb + lane];
        const float cr = C_re[hb + lane], ci = C_im[hb + lane];
        float sr = cr * br - ci * bi;
        float si = cr * bi + ci * br;
        #pragma unroll
        for (int off = 32; off > 0; off >>= 1) {
            sr += __shfl_xor(sr, off);
            si += __shfl_xor(si, off);
        }
        if (tid == 0)
            kf[h * LF + MDIM] = make_float2(0.5f * dt * sr, 0.5f * dt * si);
    }

    // ---- per-lane constants: pole params for this lane's 16 n + A frags ----
    float nwr_[16], wi_[16];
    int   av[4][4];                 // A fragment dwords (2 f16 each)
    {
        const bool arow = (m < 8);
        const int  ai   = m >> 1;   // 0:C*B 1:C*P 2:Q*B 3:Q*P
        const int  c    = m & 1;    // 0:re-row 1:im-row
        const float* fre = (ai >= 2) ? Q_re : C_re;
        const float* fim = (ai >= 2) ? Q_im : C_im;
        const float* sre = (ai & 1) ? P_re : B_re;
        const float* sim = (ai & 1) ? P_im : B_im;
        #pragma unroll
        for (int q = 0; q < 4; ++q) {
            #pragma unroll
            for (int t = 0; t < 4; ++t) {
                const int n = hb + 16 * q + 4 * g + t;
                nwr_[q * 4 + t] = -w_re[n] * dt;   // > 0
                wi_[q * 4 + t]  =  w_im[n] * dt;
                float e0 = 0.f, e1 = 0.f;
                if (arow) {
                    const float fr = fre[n], fi = fim[n];
                    const float s2r = sre[n], s2i = sim[n];
                    const float vr = fr * s2r - fi * s2i;
                    const float vi = fr * s2i + fi * s2r;
                    e0 = c ? vi : vr;
                    e1 = c ? vr : -vi;
                }
                av[q][t] = cvt_pk_f16(e0, e1);
            }
        }
    }

    // wave handles 8 l-tiles of 16: l = bx*512 + wave*128 + t8*16 + m
    const int lbase = blockIdx.x * 512 + wave * 128 + m;

    // half-angle twiddle state: (ch, sh) = cos/sin(pi*l/8192)
    float ch, sh;
    {
        const float a0 = (3.14159265358979323846f / (float)LDIM) * (float)lbase;
        sincosf(a0, &sh, &ch);
    }
    const float cd = 0.99998117528260114265f;   // cos(pi/512)
    const float sd = 0.00613588464915447536f;   // sin(pi/512)

    #pragma unroll 2
    for (int t8 = 0; t8 < 8; ++t8) {
        const float zt = 2.f * sh * __builtin_amdgcn_rcpf(ch);  // 2 tan(th/2)

        f32x4 acc = {0.f, 0.f, 0.f, 0.f};
        #pragma unroll
        for (int q = 0; q < 4; ++q) {
            int bv[4];
            #pragma unroll
            for (int t = 0; t < 4; ++t) {
                const float nwr = nwr_[q * 4 + t];
                const float tim = zt - wi_[q * 4 + t];     // Im(z - wdt)
                const float den = fmaf(tim, tim, nwr * nwr);
                const float rc  = __builtin_amdgcn_rcpf(den);
                bv[t] = cvt_pk_f16(nwr * rc, -(tim * rc)); // (Re,Im) of G
            }
            union { int i[4]; f16x8 v; } ua, ub;
            ua.i[0] = av[q][0]; ua.i[1] = av[q][1];
            ua.i[2] = av[q][2]; ua.i[3] = av[q][3];
            ub.i[0] = bv[0]; ub.i[1] = bv[1]; ub.i[2] = bv[2]; ub.i[3] = bv[3];
            acc = __builtin_amdgcn_mfma_f32_16x16x32_f16(ua.v, ub.v, acc, 0, 0, 0);
        }

        // ---- epilogue: lanes 0-15 hold V00,V01; 16-31 hold V10,V11 ----
        const float o0 = __shfl_xor(acc[0], 16);
        const float o1 = __shfl_xor(acc[1], 16);
        const float o2 = __shfl_xor(acc[2], 16);
        const float o3 = __shfl_xor(acc[3], 16);
        if (lane < 16) {
            const int l = lbase + t8 * 16;
            // num = V01 * V10 ; d = 1 + dt*V11
            const float numr = acc[2] * o0 - acc[3] * o1;
            const float numi = acc[2] * o1 + acc[3] * o0;
            const float d_r  = 1.f + dt * o2;
            const float d_i  = dt * o3;
            const float dd   = fmaf(d_r, d_r, d_i * d_i);
            const float rr2  = __builtin_amdgcn_rcpf(dd);
            const float cr = dt * ((numr * d_r + numi * d_i) * rr2);
            const float ci = dt * ((numi * d_r - numr * d_i) * rr2);
            const float Tr = acc[0] - cr;
            const float Ti = acc[1] - ci;
            // E = dt * (1, zt/2)
            const float Ei = 0.5f * dt * zt;
            kf[h * LF + l] = make_float2(dt * Tr - Ei * Ti, dt * Ti + Ei * Tr);
        }

        // rotate half-angle state by pi/512 (16 l-steps)
        const float chn = ch * cd - sh * sd;
        const float shn = sh * cd + ch * sd;
        ch = chn; sh = shn;
    }
}

// ---------------------------------------------------------------------------
// Stage B: inverse rfft via complex iFFT of size M = L/2. (unchanged, ~5 us)
// ---------------------------------------------------------------------------
__global__ __launch_bounds__(1024) void ifft_kernel(
    const float2* __restrict__ kf, float2* __restrict__ out2)
{
    __shared__ float2 S[MDIM];          // 32 KB

    const int h   = blockIdx.x;
    const int tid = threadIdx.x;
    const float2* K = kf + (size_t)h * LF;

    // ---- build Z (bit-reversed) from Hermitian half-spectrum ----
    for (int l = tid; l <= MDIM / 2; l += 1024) {
        const float2 Kl = K[l];
        const float2 Km = K[MDIM - l];
        const float Ar = 0.5f * (Kl.x + Km.x);
        const float Ai = 0.5f * (Kl.y - Km.y);
        const float Br = 0.5f * (Kl.x - Km.x);
        const float Bi = 0.5f * (Kl.y + Km.y);
        const float phi = (6.28318530717958647692f / (float)LDIM) * (float)l;
        float s, c;
        sincosf(phi, &s, &c);
        const float Or = c * Br - s * Bi;
        const float Oi = c * Bi + s * Br;
        const int bl = (int)(__brev((unsigned)l) >> (32 - LOG2M));
        S[bl] = make_float2(Ar - Oi, Ai + Or);
        if (l > 0 && l < MDIM / 2) {
            const int bm = (int)(__brev((unsigned)(MDIM - l)) >> (32 - LOG2M));
            S[bm] = make_float2(Ar + Oi, Or - Ai);
        }
    }

    // ---- 12 radix-2 DIT stages, inverse twiddles ----
    #pragma unroll
    for (int stage = 0; stage < LOG2M; ++stage) {
        const int half = 1 << stage;
        __syncthreads();
        #pragma unroll 2
        for (int t = tid; t < MDIM / 2; t += 1024) {
            const int pos = t & (half - 1);
            const int i0  = ((t & ~(half - 1)) << 1) | pos;
            const int i1  = i0 + half;
            const float ang = (3.14159265358979323846f / (float)half) * (float)pos;
            float s, c;
            sincosf(ang, &s, &c);
            const float2 a = S[i0];
            const float2 b = S[i1];
            const float tr = c * b.x - s * b.y;
            const float ti = c * b.y + s * b.x;
            S[i0] = make_float2(a.x + tr, a.y + ti);
            S[i1] = make_float2(a.x - tr, a.y - ti);
        }
    }
    __syncthreads();

    const float invM = 1.f / (float)MDIM;
    for (int n = tid; n < MDIM; n += 1024) {
        const float2 z = S[n];
        out2[(size_t)h * MDIM + n] = make_float2(z.x * invM, z.y * invM);
    }
}

extern "C" void kernel_launch(void* const* d_in, const int* in_sizes, int n_in,
                              void* d_out, int out_size, void* d_ws, size_t ws_size,
                              hipStream_t stream)
{
    const float* log_dt = (const float*)d_in[0];
    const float* C_re   = (const float*)d_in[1];
    const float* C_im   = (const float*)d_in[2];
    const float* B_re   = (const float*)d_in[3];
    const float* B_im   = (const float*)d_in[4];
    const float* P_re   = (const float*)d_in[5];
    const float* P_im   = (const float*)d_in[6];
    const float* Q_re   = (const float*)d_in[7];
    const float* Q_im   = (const float*)d_in[8];
    const float* w_re   = (const float*)d_in[9];
    const float* w_im   = (const float*)d_in[10];

    float2* kf = (float2*)d_ws;          // HDIM * LF * 8 B = 8.39 MB (in ws)
    float2* out2 = (float2*)d_out;

    dim3 grid1(8, HDIM);                 // 8 x 256 = 2048 blocks, 512 l each
    cauchy_kernel<<<grid1, 256, 0, stream>>>(log_dt, C_re, C_im, B_re, B_im,
                                             P_re, P_im, Q_re, Q_im,
                                             w_re, w_im, kf);

    ifft_kernel<<<HDIM, 1024, 0, stream>>>(kf, out2);
}

// Round 13
// 46.880 us; speedup vs baseline: 1.4829x; 1.0840x over previous
//
#include <hip/hip_runtime.h>
#include <hip/hip_fp16.h>
#include <math.h>

// Problem constants (fixed by the harness's setup_inputs)
#define HDIM 256
#define NDIM 64
#define LDIM 8192
#define LF   4097          // L/2 + 1
#define MDIM 4096          // L/2  (complex FFT size)
#define LOG2M 12
#define TWN  2048          // twiddle table entries (MDIM/2)

typedef _Float16 f16x8 __attribute__((ext_vector_type(8)));
typedef float    f32x4 __attribute__((ext_vector_type(4)));

// round-nearest f32 pair -> packed f16 dword
__device__ __forceinline__ int cvt_pk_f16(float lo, float hi) {
    union { __half2 h; int i; } u;
    u.h = __floats2half2_rn(lo, hi);
    return u.i;
}

// ---------------------------------------------------------------------------
// Stage A (R13): MFMA Cauchy with z-substitution. Same math as R12:
//   G[l,n] = 1/(i*zt - wdt), V_ab = sum_n v_ab G  (MFMA, K=128 re/im packing)
//   k_f = E * [V00 - dt*V01*V10/(1 + dt*V11)],  E = dt*(1, zt/2), zt=2tan(th/2)
// R13 deltas:
//   - launch_bounds(256,4): R12's (256,6) capped VGPR at ~85 and SPILLED the
//     48-dword constant set (WRITE_SIZE 17.6MB vs 8.4MB output = scratch).
//   - MFMA chain split into 2 independent accumulators (halve dep latency).
// ---------------------------------------------------------------------------
__global__ __launch_bounds__(256, 4) void cauchy_kernel(
    const float* __restrict__ log_dt,
    const float* __restrict__ C_re, const float* __restrict__ C_im,
    const float* __restrict__ B_re, const float* __restrict__ B_im,
    const float* __restrict__ P_re, const float* __restrict__ P_im,
    const float* __restrict__ Q_re, const float* __restrict__ Q_im,
    const float* __restrict__ w_re, const float* __restrict__ w_im,
    float2* __restrict__ kf)
{
    const int h    = blockIdx.y;
    const int tid  = threadIdx.x;
    const int lane = tid & 63;
    const int wave = tid >> 6;
    const int g    = lane >> 4;     // k-block index (0..3)
    const int m    = lane & 15;     // col (l-offset) and A-row index
    const float dt = expf(log_dt[h]);
    const int hb   = h * NDIM;

    // Nyquist bin (l = 4096): omega=-1 -> D=4, (1+omega)=0 =>
    // k_f = 0.5*dt*sum_n v00[n]; Woodbury term vanishes.
    if (blockIdx.x == 0 && tid < 64) {
        const float br = B_re[hb + lane], bi = B_im[hb + lane];
        const float cr = C_re[hb + lane], ci = C_im[hb + lane];
        float sr = cr * br - ci * bi;
        float si = cr * bi + ci * br;
        #pragma unroll
        for (int off = 32; off > 0; off >>= 1) {
            sr += __shfl_xor(sr, off);
            si += __shfl_xor(si, off);
        }
        if (tid == 0)
            kf[h * LF + MDIM] = make_float2(0.5f * dt * sr, 0.5f * dt * si);
    }

    // ---- per-lane constants: pole params for this lane's 16 n + A frags ----
    float nwr_[16], wi_[16];
    int   av[4][4];                 // A fragment dwords (2 f16 each)
    {
        const bool arow = (m < 8);
        const int  ai   = m >> 1;   // 0:C*B 1:C*P 2:Q*B 3:Q*P
        const int  c    = m & 1;    // 0:re-row 1:im-row
        const float* fre = (ai >= 2) ? Q_re : C_re;
        const float* fim = (ai >= 2) ? Q_im : C_im;
        const float* sre = (ai & 1) ? P_re : B_re;
        const float* sim = (ai & 1) ? P_im : B_im;
        #pragma unroll
        for (int q = 0; q < 4; ++q) {
            #pragma unroll
            for (int t = 0; t < 4; ++t) {
                const int n = hb + 16 * q + 4 * g + t;
                nwr_[q * 4 + t] = -w_re[n] * dt;   // > 0
                wi_[q * 4 + t]  =  w_im[n] * dt;
                float e0 = 0.f, e1 = 0.f;
                if (arow) {
                    const float fr = fre[n], fi = fim[n];
                    const float s2r = sre[n], s2i = sim[n];
                    const float vr = fr * s2r - fi * s2i;
                    const float vi = fr * s2i + fi * s2r;
                    e0 = c ? vi : vr;
                    e1 = c ? vr : -vi;
                }
                av[q][t] = cvt_pk_f16(e0, e1);
            }
        }
    }

    // wave handles 8 l-tiles of 16: l = bx*512 + wave*128 + t8*16 + m
    const int lbase = blockIdx.x * 512 + wave * 128 + m;

    // half-angle twiddle state: (ch, sh) = cos/sin(pi*l/8192)
    float ch, sh;
    {
        const float a0 = (3.14159265358979323846f / (float)LDIM) * (float)lbase;
        sincosf(a0, &sh, &ch);
    }
    const float cd = 0.99998117528260114265f;   // cos(pi/512)
    const float sd = 0.00613588464915447536f;   // sin(pi/512)

    #pragma unroll 2
    for (int t8 = 0; t8 < 8; ++t8) {
        const float zt = 2.f * sh * __builtin_amdgcn_rcpf(ch);  // 2 tan(th/2)

        f32x4 acc0 = {0.f, 0.f, 0.f, 0.f};
        f32x4 acc1 = {0.f, 0.f, 0.f, 0.f};
        #pragma unroll
        for (int q = 0; q < 4; ++q) {
            int bv[4];
            #pragma unroll
            for (int t = 0; t < 4; ++t) {
                const float nwr = nwr_[q * 4 + t];
                const float tim = zt - wi_[q * 4 + t];     // Im(z - wdt)
                const float den = fmaf(tim, tim, nwr * nwr);
                const float rc  = __builtin_amdgcn_rcpf(den);
                bv[t] = cvt_pk_f16(nwr * rc, -(tim * rc)); // (Re,Im) of G
            }
            union { int i[4]; f16x8 v; } ua, ub;
            ua.i[0] = av[q][0]; ua.i[1] = av[q][1];
            ua.i[2] = av[q][2]; ua.i[3] = av[q][3];
            ub.i[0] = bv[0]; ub.i[1] = bv[1]; ub.i[2] = bv[2]; ub.i[3] = bv[3];
            if (q < 2)
                acc0 = __builtin_amdgcn_mfma_f32_16x16x32_f16(ua.v, ub.v, acc0, 0, 0, 0);
            else
                acc1 = __builtin_amdgcn_mfma_f32_16x16x32_f16(ua.v, ub.v, acc1, 0, 0, 0);
        }
        const f32x4 acc = acc0 + acc1;

        // ---- epilogue: lanes 0-15 hold V00,V01; 16-31 hold V10,V11 ----
        const float o0 = __shfl_xor(acc[0], 16);
        const float o1 = __shfl_xor(acc[1], 16);
        const float o2 = __shfl_xor(acc[2], 16);
        const float o3 = __shfl_xor(acc[3], 16);
        if (lane < 16) {
            const int l = lbase + t8 * 16;
            // num = V01 * V10 ; d = 1 + dt*V11
            const float numr = acc[2] * o0 - acc[3] * o1;
            const float numi = acc[2] * o1 + acc[3] * o0;
            const float d_r  = 1.f + dt * o2;
            const float d_i  = dt * o3;
            const float dd   = fmaf(d_r, d_r, d_i * d_i);
            const float rr2  = __builtin_amdgcn_rcpf(dd);
            const float cr = dt * ((numr * d_r + numi * d_i) * rr2);
            const float ci = dt * ((numi * d_r - numr * d_i) * rr2);
            const float Tr = acc[0] - cr;
            const float Ti = acc[1] - ci;
            // E = dt * (1, zt/2)
            const float Ei = 0.5f * dt * zt;
            kf[h * LF + l] = make_float2(dt * Tr - Ei * Ti, dt * Ti + Ei * Tr);
        }

        // rotate half-angle state by pi/512 (16 l-steps)
        const float chn = ch * cd - sh * sd;
        const float shn = sh * cd + ch * sd;
        ch = chn; sh = shn;
    }
}

// ---------------------------------------------------------------------------
// Stage B: inverse rfft via complex iFFT of size M = L/2.
// R13: LDS twiddle table (2048 entries, index-padded i+(i>>4) so power-of-2
// stage strides spread across banks) replaces 24 sincosf/thread.
// ---------------------------------------------------------------------------
__device__ __forceinline__ int twpad(int i) { return i + (i >> 4); }

__global__ __launch_bounds__(1024) void ifft_kernel(
    const float2* __restrict__ kf, float2* __restrict__ out2)
{
    __shared__ float2 S[MDIM];               // 32 KB
    __shared__ float2 TW[TWN + TWN / 16];    // 17 KB, padded

    const int h   = blockIdx.x;
    const int tid = threadIdx.x;
    const float2* K = kf + (size_t)h * LF;

    // ---- build twiddle table: TW[p] = e^{+i*pi*p/2048} ----
    for (int p = tid; p < TWN; p += 1024) {
        float s, c;
        sincosf((3.14159265358979323846f / (float)TWN) * (float)p, &s, &c);
        TW[twpad(p)] = make_float2(c, s);
    }

    // ---- build Z (bit-reversed) from Hermitian half-spectrum ----
    for (int l = tid; l <= MDIM / 2; l += 1024) {
        const float2 Kl = K[l];
        const float2 Km = K[MDIM - l];
        const float Ar = 0.5f * (Kl.x + Km.x);
        const float Ai = 0.5f * (Kl.y - Km.y);
        const float Br = 0.5f * (Kl.x - Km.x);
        const float Bi = 0.5f * (Kl.y + Km.y);
        const float phi = (6.28318530717958647692f / (float)LDIM) * (float)l;
        float s, c;
        sincosf(phi, &s, &c);
        const float Or = c * Br - s * Bi;
        const float Oi = c * Bi + s * Br;
        const int bl = (int)(__brev((unsigned)l) >> (32 - LOG2M));
        S[bl] = make_float2(Ar - Oi, Ai + Or);
        if (l > 0 && l < MDIM / 2) {
            const int bm = (int)(__brev((unsigned)(MDIM - l)) >> (32 - LOG2M));
            S[bm] = make_float2(Ar + Oi, Or - Ai);
        }
    }

    // ---- 12 radix-2 DIT stages, inverse twiddles from the table ----
    #pragma unroll
    for (int stage = 0; stage < LOG2M; ++stage) {
        const int half = 1 << stage;
        __syncthreads();
        #pragma unroll 2
        for (int t = tid; t < MDIM / 2; t += 1024) {
            const int pos = t & (half - 1);
            const int i0  = ((t & ~(half - 1)) << 1) | pos;
            const int i1  = i0 + half;
            const float2 w = TW[twpad(pos << (11 - stage))];  // e^{+i pi pos/half}
            const float2 a = S[i0];
            const float2 b = S[i1];
            const float tr = w.x * b.x - w.y * b.y;
            const float ti = w.x * b.y + w.y * b.x;
            S[i0] = make_float2(a.x + tr, a.y + ti);
            S[i1] = make_float2(a.x - tr, a.y - ti);
        }
    }
    __syncthreads();

    const float invM = 1.f / (float)MDIM;
    for (int n = tid; n < MDIM; n += 1024) {
        const float2 z = S[n];
        out2[(size_t)h * MDIM + n] = make_float2(z.x * invM, z.y * invM);
    }
}

extern "C" void kernel_launch(void* const* d_in, const int* in_sizes, int n_in,
                              void* d_out, int out_size, void* d_ws, size_t ws_size,
                              hipStream_t stream)
{
    const float* log_dt = (const float*)d_in[0];
    const float* C_re   = (const float*)d_in[1];
    const float* C_im   = (const float*)d_in[2];
    const float* B_re   = (const float*)d_in[3];
    const float* B_im   = (const float*)d_in[4];
    const float* P_re   = (const float*)d_in[5];
    const float* P_im   = (const float*)d_in[6];
    const float* Q_re   = (const float*)d_in[7];
    const float* Q_im   = (const float*)d_in[8];
    const float* w_re   = (const float*)d_in[9];
    const float* w_im   = (const float*)d_in[10];

    float2* kf = (float2*)d_ws;          // HDIM * LF * 8 B = 8.39 MB (in ws)
    float2* out2 = (float2*)d_out;

    dim3 grid1(8, HDIM);                 // 8 x 256 = 2048 blocks, 512 l each
    cauchy_kernel<<<grid1, 256, 0, stream>>>(log_dt, C_re, C_im, B_re, B_im,
                                             P_re, P_im, Q_re, Q_im,
                                             w_re, w_im, kf);

    ifft_kernel<<<HDIM, 1024, 0, stream>>>(kf, out2);
}

// Round 15
// 38.142 us; speedup vs baseline: 1.8226x; 1.2291x over previous
//
#include <hip/hip_runtime.h>
#include <hip/hip_fp16.h>
#include <math.h>

// Problem constants (fixed by the harness's setup_inputs)
#define HDIM 256
#define NDIM 64
#define LDIM 8192
#define LF   4097          // L/2 + 1
#define MDIM 4096          // L/2  (complex FFT size)
#define LOG2M 12
#define TWN  2048          // twiddle table entries (MDIM/2)

typedef _Float16 f16x8 __attribute__((ext_vector_type(8)));
typedef __fp16   fp16x2 __attribute__((ext_vector_type(2)));   // pkrtz return type
typedef float    f32x4 __attribute__((ext_vector_type(4)));

// round-nearest f32 pair -> packed f16 dword (3 instr; used once, A frags)
__device__ __forceinline__ int cvt_pk_f16(float lo, float hi) {
    union { __half2 h; int i; } u;
    u.h = __floats2half2_rn(lo, hi);
    return u.i;
}
// single-instruction RTZ pack (hot path, B frags)
__device__ __forceinline__ int cvt_pkrtz(float lo, float hi) {
    union { fp16x2 h; int i; } u;
    u.h = __builtin_amdgcn_cvt_pkrtz(lo, hi);
    return u.i;
}

__device__ __forceinline__ int twpad(int i) { return i + (i >> 4); }

// ---------------------------------------------------------------------------
// R15 (= R14 + type fix): FUSED cauchy + irfft. One block (1024 thr) per head.
//
// Phase 1 (cauchy, MFMA): same math as R12/R13 —
//   G[l,n] = 1/(i*zt - wdt), V_ab = sum_n v_ab G  (K=128 re/im packed MFMA)
//   k_f = E * [V00 - dt*V01*V10/(1 + dt*V11)], E = dt*(1, zt/2), zt=2tan(th/2)
//   B-build: 6 instr/cell (nwr^2 precomputed, v_cvt_pkrtz single-instr pack).
//   Wave w owns l = w*256 + t*16 + (lane&15), t = 0..15. Writes kf to LDS.
// Phase 2 (irfft): Hermitian pack -> 12 radix-2 DIT stages in LDS (twiddle
//   table, padded indices) -> interleaved real store. kf never touches HBM;
//   one launch total; d_ws unused.
// ---------------------------------------------------------------------------
__global__ __launch_bounds__(1024, 4) void fused_kernel(
    const float* __restrict__ log_dt,
    const float* __restrict__ C_re, const float* __restrict__ C_im,
    const float* __restrict__ B_re, const float* __restrict__ B_im,
    const float* __restrict__ P_re, const float* __restrict__ P_im,
    const float* __restrict__ Q_re, const float* __restrict__ Q_im,
    const float* __restrict__ w_re, const float* __restrict__ w_im,
    float2* __restrict__ out2)
{
    __shared__ float2 kfs[LF];               // 32.8 KB
    __shared__ float2 S[MDIM];               // 32 KB
    __shared__ float2 TW[TWN + TWN / 16];    // 17.4 KB

    const int h    = blockIdx.x;
    const int tid  = threadIdx.x;
    const int lane = tid & 63;
    const int wave = tid >> 6;
    const int g    = lane >> 4;     // k-block index (0..3)
    const int m    = lane & 15;     // col (l-offset) and A-row index
    const float dt = expf(log_dt[h]);
    const int hb   = h * NDIM;

    // ---- twiddle table: TW[p] = e^{+i*pi*p/2048} ----
    for (int p = tid; p < TWN; p += 1024) {
        float s, c;
        sincosf((3.14159265358979323846f / (float)TWN) * (float)p, &s, &c);
        TW[twpad(p)] = make_float2(c, s);
    }

    // ---- Nyquist bin (l = 4096): k_f = 0.5*dt*sum_n v00[n] ----
    if (tid < 64) {
        const float br = B_re[hb + lane], bi = B_im[hb + lane];
        const float cr = C_re[hb + lane], ci = C_im[hb + lane];
        float sr = cr * br - ci * bi;
        float si = cr * bi + ci * br;
        #pragma unroll
        for (int off = 32; off > 0; off >>= 1) {
            sr += __shfl_xor(sr, off);
            si += __shfl_xor(si, off);
        }
        if (tid == 0)
            kfs[MDIM] = make_float2(0.5f * dt * sr, 0.5f * dt * si);
    }

    // ---- per-lane constants: pole params for this lane's 16 n + A frags ----
    float nwr_[16], nw2_[16], wi_[16];
    int   av[4][4];                 // A fragment dwords (2 f16 each)
    {
        const bool arow = (m < 8);
        const int  ai   = m >> 1;   // 0:C*B 1:C*P 2:Q*B 3:Q*P
        const int  c    = m & 1;    // 0:re-row 1:im-row
        const float* fre = (ai >= 2) ? Q_re : C_re;
        const float* fim = (ai >= 2) ? Q_im : C_im;
        const float* sre = (ai & 1) ? P_re : B_re;
        const float* sim = (ai & 1) ? P_im : B_im;
        #pragma unroll
        for (int q = 0; q < 4; ++q) {
            #pragma unroll
            for (int t = 0; t < 4; ++t) {
                const int n = hb + 16 * q + 4 * g + t;
                const float nw = -w_re[n] * dt;    // > 0
                nwr_[q * 4 + t] = nw;
                nw2_[q * 4 + t] = nw * nw;
                wi_[q * 4 + t]  = w_im[n] * dt;
                float e0 = 0.f, e1 = 0.f;
                if (arow) {
                    const float fr = fre[n], fi = fim[n];
                    const float s2r = sre[n], s2i = sim[n];
                    const float vr = fr * s2r - fi * s2i;
                    const float vi = fr * s2i + fi * s2r;
                    e0 = c ? vi : vr;
                    e1 = c ? vr : -vi;
                }
                av[q][t] = cvt_pk_f16(e0, e1);
            }
        }
    }

    // ---- cauchy phase: wave owns l = wave*256 + t*16 + m, t = 0..15 ----
    const int lbase = wave * 256 + m;

    float ch, sh;   // half-angle state: cos/sin(pi*l/8192)
    {
        const float a0 = (3.14159265358979323846f / (float)LDIM) * (float)lbase;
        sincosf(a0, &sh, &ch);
    }
    const float cd = 0.99998117528260114265f;   // cos(pi/512)
    const float sd = 0.00613588464915447536f;   // sin(pi/512)

    #pragma unroll 2
    for (int t16 = 0; t16 < 16; ++t16) {
        const float zt = 2.f * sh * __builtin_amdgcn_rcpf(ch);  // 2 tan(th/2)

        f32x4 acc0 = {0.f, 0.f, 0.f, 0.f};
        f32x4 acc1 = {0.f, 0.f, 0.f, 0.f};
        #pragma unroll
        for (int q = 0; q < 4; ++q) {
            int bv[4];
            #pragma unroll
            for (int t = 0; t < 4; ++t) {
                const float tim = zt - wi_[q * 4 + t];     // Im(z - wdt)
                const float den = fmaf(tim, tim, nw2_[q * 4 + t]);
                const float rc  = __builtin_amdgcn_rcpf(den);
                bv[t] = cvt_pkrtz(nwr_[q * 4 + t] * rc, -(tim * rc));
            }
            union { int i[4]; f16x8 v; } ua, ub;
            ua.i[0] = av[q][0]; ua.i[1] = av[q][1];
            ua.i[2] = av[q][2]; ua.i[3] = av[q][3];
            ub.i[0] = bv[0]; ub.i[1] = bv[1]; ub.i[2] = bv[2]; ub.i[3] = bv[3];
            if (q < 2)
                acc0 = __builtin_amdgcn_mfma_f32_16x16x32_f16(ua.v, ub.v, acc0, 0, 0, 0);
            else
                acc1 = __builtin_amdgcn_mfma_f32_16x16x32_f16(ua.v, ub.v, acc1, 0, 0, 0);
        }
        const f32x4 acc = acc0 + acc1;

        // epilogue: lanes 0-15 hold V00,V01; 16-31 hold V10,V11
        const float o0 = __shfl_xor(acc[0], 16);
        const float o1 = __shfl_xor(acc[1], 16);
        const float o2 = __shfl_xor(acc[2], 16);
        const float o3 = __shfl_xor(acc[3], 16);
        if (lane < 16) {
            const int l = lbase + t16 * 16;
            const float numr = acc[2] * o0 - acc[3] * o1;
            const float numi = acc[2] * o1 + acc[3] * o0;
            const float d_r  = 1.f + dt * o2;
            const float d_i  = dt * o3;
            const float dd   = fmaf(d_r, d_r, d_i * d_i);
            const float rr2  = __builtin_amdgcn_rcpf(dd);
            const float cr = dt * ((numr * d_r + numi * d_i) * rr2);
            const float ci = dt * ((numi * d_r - numr * d_i) * rr2);
            const float Tr = acc[0] - cr;
            const float Ti = acc[1] - ci;
            const float Ei = 0.5f * dt * zt;            // E = dt*(1, zt/2)
            kfs[l] = make_float2(dt * Tr - Ei * Ti, dt * Ti + Ei * Tr);
        }

        // rotate half-angle state by pi/512 (16 l-steps)
        const float chn = ch * cd - sh * sd;
        const float shn = sh * cd + ch * sd;
        ch = chn; sh = shn;
    }

    __syncthreads();

    // ---- irfft phase: Hermitian pack (from LDS kfs) into bit-reversed Z ----
    for (int l = tid; l <= MDIM / 2; l += 1024) {
        const float2 Kl = kfs[l];
        const float2 Km = kfs[MDIM - l];
        const float Ar = 0.5f * (Kl.x + Km.x);
        const float Ai = 0.5f * (Kl.y - Km.y);
        const float Br = 0.5f * (Kl.x - Km.x);
        const float Bi = 0.5f * (Kl.y + Km.y);
        const float phi = (6.28318530717958647692f / (float)LDIM) * (float)l;
        float s, c;
        sincosf(phi, &s, &c);
        const float Or = c * Br - s * Bi;
        const float Oi = c * Bi + s * Br;
        const int bl = (int)(__brev((unsigned)l) >> (32 - LOG2M));
        S[bl] = make_float2(Ar - Oi, Ai + Or);
        if (l > 0 && l < MDIM / 2) {
            const int bm = (int)(__brev((unsigned)(MDIM - l)) >> (32 - LOG2M));
            S[bm] = make_float2(Ar + Oi, Or - Ai);
        }
    }

    // ---- 12 radix-2 DIT stages, inverse twiddles from the table ----
    #pragma unroll
    for (int stage = 0; stage < LOG2M; ++stage) {
        const int half = 1 << stage;
        __syncthreads();
        #pragma unroll 2
        for (int t = tid; t < MDIM / 2; t += 1024) {
            const int pos = t & (half - 1);
            const int i0  = ((t & ~(half - 1)) << 1) | pos;
            const int i1  = i0 + half;
            const float2 w = TW[twpad(pos << (11 - stage))];
            const float2 a = S[i0];
            const float2 b = S[i1];
            const float tr = w.x * b.x - w.y * b.y;
            const float ti = w.x * b.y + w.y * b.x;
            S[i0] = make_float2(a.x + tr, a.y + ti);
            S[i1] = make_float2(a.x - tr, a.y - ti);
        }
    }
    __syncthreads();

    const float invM = 1.f / (float)MDIM;
    for (int n = tid; n < MDIM; n += 1024) {
        const float2 z = S[n];
        out2[(size_t)h * MDIM + n] = make_float2(z.x * invM, z.y * invM);
    }
}

extern "C" void kernel_launch(void* const* d_in, const int* in_sizes, int n_in,
                              void* d_out, int out_size, void* d_ws, size_t ws_size,
                              hipStream_t stream)
{
    const float* log_dt = (const float*)d_in[0];
    const float* C_re   = (const float*)d_in[1];
    const float* C_im   = (const float*)d_in[2];
    const float* B_re   = (const float*)d_in[3];
    const float* B_im   = (const float*)d_in[4];
    const float* P_re   = (const float*)d_in[5];
    const float* P_im   = (const float*)d_in[6];
    const float* Q_re   = (const float*)d_in[7];
    const float* Q_im   = (const float*)d_in[8];
    const float* w_re   = (const float*)d_in[9];
    const float* w_im   = (const float*)d_in[10];

    float2* out2 = (float2*)d_out;

    fused_kernel<<<HDIM, 1024, 0, stream>>>(log_dt, C_re, C_im, B_re, B_im,
                                            P_re, P_im, Q_re, Q_im,
                                            w_re, w_im, out2);
}